// Round 3
// baseline (805.182 us; speedup 1.0000x reference)
//
#include <hip/hip_runtime.h>

// article_concat: [256, 2048, 300] fp32  (d_in[0])
// options_concat: [256,   64, 300] fp32  (d_in[1])
// out:            [256, 600]       fp32
//
// Single fused kernel: one block per batch element b, 600 threads.
// 600 % 75 == 0, so reading the article[b] slab as a flat float4 stream
// (f = it*600 + t) keeps each thread's float4-column j = t%75 constant ->
// pure register accumulation over a contiguous 2.4 MB stream per block,
// fully coalesced, 16 loads in flight (4 accumulators x 4 loads x unroll 4).
// Options[b] (75 KB) same trick, 8 loads fully unrolled.
// One LDS reduce over the 8 row-phase groups, threads 0..74 write both
// float4 output slices directly. No workspace, no second kernel.

typedef float f4 __attribute__((ext_vector_type(4)));

#define B        256
#define DIM      300
#define J4       75                        // DIM/4 float4 columns
#define W_ART    2048
#define W_OPT    64
#define THR      600                       // block size; THR % J4 == 0
#define GRP      (THR / J4)                // 8 row-phase groups
#define ART_F4   (W_ART * J4)              // 153600 float4 per batch
#define ART_IT   (ART_F4 / THR)            // 256 loads per thread
#define OPT_F4   (W_OPT * J4)              // 4800 float4 per batch
#define OPT_IT   (OPT_F4 / THR)            // 8 loads per thread

__global__ __launch_bounds__(THR) void fused_mean_kernel(
    const f4* __restrict__ art,            // [B][2048][75]
    const f4* __restrict__ opt,            // [B][64][75]
    f4* __restrict__ out)                  // [B][150]
{
    const int b = blockIdx.x;
    const int t = threadIdx.x;

    // ---- article: 256 float4 loads/thread, column t%75 constant ----
    const f4* pa = art + (size_t)b * ART_F4 + t;
    f4 a0 = {0.f, 0.f, 0.f, 0.f};
    f4 a1 = {0.f, 0.f, 0.f, 0.f};
    f4 a2 = {0.f, 0.f, 0.f, 0.f};
    f4 a3 = {0.f, 0.f, 0.f, 0.f};
    #pragma unroll 4
    for (int it = 0; it < ART_IT; it += 4, pa += 4 * THR) {
        const f4 v0 = pa[0 * THR];
        const f4 v1 = pa[1 * THR];
        const f4 v2 = pa[2 * THR];
        const f4 v3 = pa[3 * THR];
        a0 += v0;
        a1 += v1;
        a2 += v2;
        a3 += v3;
    }
    a0 += a1; a2 += a3; a0 += a2;

    // ---- options: 8 float4 loads/thread, fully unrolled ----
    const f4* po = opt + (size_t)b * OPT_F4 + t;
    f4 o0 = {0.f, 0.f, 0.f, 0.f};
    f4 o1 = {0.f, 0.f, 0.f, 0.f};
    #pragma unroll
    for (int it = 0; it < OPT_IT; it += 2, po += 2 * THR) {
        o0 += po[0];
        o1 += po[THR];
    }
    o0 += o1;

    // ---- LDS reduce over the 8 row-phase groups per column ----
    __shared__ f4 lart[THR];
    __shared__ f4 lopt[THR];
    lart[t] = a0;
    lopt[t] = o0;
    __syncthreads();

    if (t < J4) {
        f4 sa = lart[t];
        f4 so = lopt[t];
        #pragma unroll
        for (int g = 1; g < GRP; ++g) {
            sa += lart[t + g * J4];
            so += lopt[t + g * J4];
        }
        f4* ou = out + (size_t)b * (2 * J4);
        ou[t]      = sa * (1.0f / (float)W_ART);
        ou[J4 + t] = so * (1.0f / (float)W_OPT);
    }
}

extern "C" void kernel_launch(void* const* d_in, const int* in_sizes, int n_in,
                              void* d_out, int out_size, void* d_ws, size_t ws_size,
                              hipStream_t stream) {
    const f4* art = (const f4*)d_in[0];
    const f4* opt = (const f4*)d_in[1];
    f4* out = (f4*)d_out;
    (void)d_ws; (void)ws_size;             // no workspace needed

    fused_mean_kernel<<<dim3(B), dim3(THR), 0, stream>>>(art, opt, out);
}